// Round 7
// baseline (411.493 us; speedup 1.0000x reference)
//
#include <hip/hip_runtime.h>
#include <stdint.h>

// BinaryDense: out[8192,4096] = x[8192,4096] @ sign(kernel[4096,4096]) + bias[4096]
// R9 (resubmit; prior round hit GPUAcquisitionTimeout — no bench ran).
// R8 proved the GEMM theory (conflicts 12.58M->0, 146->127us) but exposed prep as
// the dominant cost: total-gemm = 268us vs a ~50us traffic floor (~1.1 TB/s
// effective -> latency/transaction-amplification-bound). Fixes:
//  prepA: (a) rowmax: wave-per-row, lane-contiguous float4 reads, shfl-only reduce,
//         stores rscale + rsinv (same bits as old in-kernel s -> absmax unchanged);
//         (b) signT: R8's 64x64 LDS tile, final write fragment-major (4x256B
//         segments/instr instead of 64x64B scattered at 4KB stride).
//  prepB: quantize + fragment-major relayout fused through a 64KB LDS band tile:
//         coalesced row-major reads (16B/lane), XOR-swizzled LDS transpose
//         (store conflict-free; read = inherent 4-pass b128 minimum), contiguous
//         64KB global write bursts. The 67MB relayout pass is gone.
// GEMM: byte-identical to R8 (fragment-major, 4-buf counted-vmcnt, 32x32x32 i8).

typedef int int4v __attribute__((ext_vector_type(4)));
typedef int int16v __attribute__((ext_vector_type(16)));

constexpr int M = 8192, N = 4096, K = 4096;
constexpr int BM = 256, BN = 256, BK = 64;  // i8 elements (= bytes)
constexpr int NT = K / BK;                  // 64 K-tiles
constexpr int BANDSZ = 131072;              // 32 rows * 4096 k bytes

__device__ __forceinline__ void gload_lds16(const void* g, void* l) {
  __builtin_amdgcn_global_load_lds(
      (const __attribute__((address_space(1))) unsigned int*)g,
      (__attribute__((address_space(3))) unsigned int*)l, 16, 0, 0);
}

#define FENCE asm volatile("" ::: "memory")

// ---- prepA: blocks [0,2048): row absmax (wave per row).
//      blocks [2048,6144): sign(w)^T -> Wq fragment-major (64x64 LDS tiles). ----
__global__ __launch_bounds__(256) void prepA_kernel(const float* __restrict__ x,
                                                    float* __restrict__ rscale,
                                                    float* __restrict__ rsinv,
                                                    const float* __restrict__ w,
                                                    signed char* __restrict__ wq) {
  const int t = threadIdx.x;
  if (blockIdx.x < 2048) {
    const int row = blockIdx.x * 4 + (t >> 6);
    const int lane = t & 63;
    const float* xr = x + (size_t)row * K;
    float mx = 0.f;
#pragma unroll
    for (int j = 0; j < 16; ++j) {
      float4 v = *(const float4*)(xr + j * 256 + lane * 4);
      mx = fmaxf(mx, fmaxf(fmaxf(fabsf(v.x), fabsf(v.y)),
                           fmaxf(fabsf(v.z), fabsf(v.w))));
    }
#pragma unroll
    for (int off = 32; off >= 1; off >>= 1)
      mx = fmaxf(mx, __shfl_xor(mx, off, 64));
    if (lane == 0) {
      rscale[row] = (mx > 0.f) ? mx / 127.f : 0.f;
      rsinv[row] = (mx > 0.f) ? 127.f / mx : 0.f;
    }
  } else {
    // sign-transpose one 64(n) x 64(k) tile of w -> fragment-major Wq.
    __shared__ __align__(16) signed char tile[64 * 68];  // pad 68
    const int idx = blockIdx.x - 2048;
    const int n0 = (idx & 63) * 64, k0 = (idx >> 6) * 64;
#pragma unroll
    for (int i = 0; i < 4; ++i) {
      int kl = (t >> 4) + i * 16;  // 0..63
      int nl = (t & 15) * 4;       // 0..60
      float4 v = *(const float4*)(w + (size_t)(k0 + kl) * N + n0 + nl);
      uint32_t p = 0;
      p |= ((uint32_t)(uint8_t)(signed char)((v.x > 0.f) - (v.x < 0.f)));
      p |= ((uint32_t)(uint8_t)(signed char)((v.y > 0.f) - (v.y < 0.f))) << 8;
      p |= ((uint32_t)(uint8_t)(signed char)((v.z > 0.f) - (v.z < 0.f))) << 16;
      p |= ((uint32_t)(uint8_t)(signed char)((v.w > 0.f) - (v.w < 0.f))) << 24;
      *(uint32_t*)(tile + kl * 68 + nl) = p;
    }
    __syncthreads();
    const int nl = t >> 2;  // 0..63
    const int ci = t & 3;   // 16B chunk within the 64-k tile
    uint32_t o[4] = {0, 0, 0, 0};
#pragma unroll
    for (int j = 0; j < 16; ++j)
      o[j >> 2] |= ((uint32_t)(uint8_t)tile[(ci * 16 + j) * 68 + nl]) << (8 * (j & 3));
    const int n = n0 + nl;
    const int nband = n >> 5, n31 = n & 31;
    const int tt = k0 >> 6;
    *(int4v*)(wq + (size_t)nband * BANDSZ + tt * 2048 + ci * 512 + n31 * 16) =
        (int4v){(int)o[0], (int)o[1], (int)o[2], (int)o[3]};
  }
}

// ---- prepB: quantize x -> Xq fragment-major, fused via 64KB LDS band tile.
//      block = (band, khalf): 32 rows x 2048 k-floats. 512 threads. ----
__global__ __launch_bounds__(512) void prepB_kernel(const float* __restrict__ x,
                                                    const float* __restrict__ rsinv,
                                                    signed char* __restrict__ xq) {
  __shared__ __align__(16) signed char lq[32 * 2048];  // 64 KB
  const int tid = threadIdx.x;
  const int band = blockIdx.x >> 1;   // 0..255
  const int h = blockIdx.x & 1;       // k-half: 2048 floats
  const int s_ = tid >> 2;            // in-row 16B out-chunk 0..127
  const int b_ = tid & 3;             // byte-quad within chunk

#pragma unroll 4
  for (int r = 0; r < 32; ++r) {
    const int row = band * 32 + r;
    const float s = rsinv[row];
    float4 v = *(const float4*)(x + (size_t)row * K + h * 2048 + tid * 4);
    uint32_t p = 0;
    {
      int q0 = (int)rintf(v.x * s);
      int q1 = (int)rintf(v.y * s);
      int q2 = (int)rintf(v.z * s);
      int q3 = (int)rintf(v.w * s);
      p = ((uint32_t)(uint8_t)(signed char)q0) |
          (((uint32_t)(uint8_t)(signed char)q1) << 8) |
          (((uint32_t)(uint8_t)(signed char)q2) << 16) |
          (((uint32_t)(uint8_t)(signed char)q3) << 24);
    }
    const int sp = (s_ & 96) | ((s_ ^ r) & 31);  // XOR low5 swizzle (bijective/row)
    *(uint32_t*)(lq + r * 2048 + sp * 16 + b_ * 4) = p;
  }
  __syncthreads();
  // write 64KB contiguous: chunk ch = ss*32 + r31 at global offset ch*16.
  const size_t obase = (size_t)band * BANDSZ + (size_t)h * 65536;
#pragma unroll
  for (int it = 0; it < 8; ++it) {
    const int ch = it * 512 + tid;
    const int ss = ch >> 5, r31 = ch & 31;
    const int sp = (ss & 96) | ((ss ^ r31) & 31);
    *(int4v*)(xq + obase + (size_t)ch * 16) =
        *(const int4v*)(lq + r31 * 2048 + sp * 16);
  }
}

// ---- kernel 3: i8 32x32x32 MFMA GEMM, fragment-major LDS, 4-buf pipeline ----
// (byte-identical to R8)

#define RD_SET(AN, BN_, P, KK)                                                 \
  {                                                                            \
    _Pragma("unroll") for (int mi_ = 0; mi_ < 4; ++mi_) {                      \
      AN[mi_] = *(const int4v*)(smem + (P)*32768 + wm * 8192 + mi_ * 2048 +    \
                                (KK)*1024 + lane16);                           \
    }                                                                          \
    _Pragma("unroll") for (int ni_ = 0; ni_ < 2; ++ni_) {                      \
      BN_[ni_] = *(const int4v*)(smem + (P)*32768 + 16384 + wn * 4096 +        \
                                 ni_ * 2048 + (KK)*1024 + lane16);             \
    }                                                                          \
  }

#define MM(AN, BN_)                                                            \
  {                                                                            \
    __builtin_amdgcn_s_setprio(1);                                             \
    _Pragma("unroll") for (int mi_ = 0; mi_ < 4; ++mi_) {                      \
      _Pragma("unroll") for (int ni_ = 0; ni_ < 2; ++ni_) {                    \
        acc[mi_][ni_] = __builtin_amdgcn_mfma_i32_32x32x32_i8(                 \
            AN[mi_], BN_[ni_], acc[mi_][ni_], 0, 0, 0);                        \
      }                                                                        \
    }                                                                          \
    __builtin_amdgcn_s_setprio(0);                                             \
  }

// one tile: P = T&3, Q = (T+1)&3, S = (T+2)&3 (compile-time buf constants).
#define TILE(P, Q, S, T)                                                       \
  {                                                                            \
    RD_SET(aY, bY, P, 1);                                                      \
    const bool more2_ = (T) + 2 < NT;                                          \
    if (more2_) stage(S, (T) + 2);                                             \
    MM(aX, bX);                                                                \
    if (more2_) {                                                              \
      asm volatile("s_waitcnt vmcnt(4)" ::: "memory");                         \
    } else {                                                                   \
      asm volatile("s_waitcnt vmcnt(0)" ::: "memory");                         \
    }                                                                          \
    __builtin_amdgcn_s_barrier();                                              \
    FENCE;                                                                     \
    if ((T) + 1 < NT) RD_SET(aX, bX, Q, 0);                                    \
    MM(aY, bY);                                                                \
    FENCE;                                                                     \
  }

__global__ __launch_bounds__(512, 2) void gemm_bin_kernel(
    const signed char* __restrict__ Xq,
    const signed char* __restrict__ Wq,
    const float* __restrict__ rscale,
    const float* __restrict__ bias,
    float* __restrict__ out) {
  __shared__ __align__(16) signed char smem[131072];

  const int tid = threadIdx.x;
  const int w = tid >> 6;
  const int lane = tid & 63;
  const int wm = w >> 2;     // 0..1 -> rows wm*128
  const int wn = w & 3;      // 0..3 -> cols wn*64
  const int hi = lane >> 5;  // k-half within 32-k step
  const int l31 = lane & 31;
  const int lane16 = lane * 16;
  const size_t m0 = (size_t)blockIdx.y * BM;
  const size_t n0 = (size_t)blockIdx.x * BN;

  int16v acc[4][2];
#pragma unroll
  for (int i = 0; i < 4; ++i)
#pragma unroll
    for (int j = 0; j < 2; ++j)
#pragma unroll
      for (int r = 0; r < 16; ++r) acc[i][j][r] = 0;
  int4v aX[4], bX[2], aY[4], bY[2];  // ping-pong operand sets

  const size_t abase0 = (m0 >> 5) * (size_t)BANDSZ;
  const size_t bbase0 = (n0 >> 5) * (size_t)BANDSZ;
  auto stage = [&](int pb, int t) {
    signed char* lb = smem + pb * 32768;
    const size_t at = abase0 + (size_t)t * 2048;
    const size_t bt = bbase0 + (size_t)t * 2048;
#pragma unroll
    for (int it = 0; it < 2; ++it) {
      int pos = it * 512 + tid;
      gload_lds16(Xq + at + (size_t)(pos >> 7) * BANDSZ + ((pos >> 6) & 1) * 1024 +
                      (pos & 63) * 16,
                  lb + pos * 16);
    }
#pragma unroll
    for (int it = 0; it < 2; ++it) {
      int pos = it * 512 + tid;
      gload_lds16(Wq + bt + (size_t)(pos >> 7) * BANDSZ + ((pos >> 6) & 1) * 1024 +
                      (pos & 63) * 16,
                  lb + 16384 + pos * 16);
    }
  };

  // prologue: stage tiles 0,1; drain tile 0 (counted); first operands.
  stage(0, 0);
  stage(1, 1);
  asm volatile("s_waitcnt vmcnt(4)" ::: "memory");
  __builtin_amdgcn_s_barrier();
  FENCE;
  RD_SET(aX, bX, 0, 0);

#pragma unroll 1
  for (int t = 0; t < NT; t += 4) {
    TILE(0, 1, 2, t)
    TILE(1, 2, 3, t + 1)
    TILE(2, 3, 0, t + 2)
    TILE(3, 0, 1, t + 3)
  }

  // epilogue: 32x32 C/D layout: col=lane&31, row=(reg&3)+8*(reg>>2)+4*(lane>>5)
#pragma unroll
  for (int mi = 0; mi < 4; ++mi) {
    const size_t rbase = m0 + wm * 128 + mi * 32;
    float sc[4][4];  // [quad q][elem j]: row = rbase + hi*4 + q*8 + j
#pragma unroll
    for (int q = 0; q < 4; ++q)
      *(float4*)sc[q] = *(const float4*)(rscale + rbase + hi * 4 + q * 8);
#pragma unroll
    for (int ni = 0; ni < 2; ++ni) {
      const size_t col = n0 + wn * 64 + ni * 32 + l31;
      const float bv = bias[col];
#pragma unroll
      for (int r = 0; r < 16; ++r) {
        const int row = (r & 3) + 8 * (r >> 2) + 4 * hi;
        out[(rbase + row) * N + col] = (float)acc[mi][ni][r] * sc[r >> 2][r & 3] + bv;
      }
    }
  }
}

extern "C" void kernel_launch(void* const* d_in, const int* in_sizes, int n_in,
                              void* d_out, int out_size, void* d_ws, size_t ws_size,
                              hipStream_t stream) {
  const float* x = (const float*)d_in[0];
  const float* kern = (const float*)d_in[1];
  const float* bias = (const float*)d_in[2];
  float* out = (float*)d_out;

  signed char* Xq = (signed char*)d_ws;                 // 32 MiB
  signed char* Wq = Xq + (size_t)M * K;                 // 16 MiB
  float* rscale = (float*)(Wq + (size_t)N * K);         // 32 KiB
  float* rsinv = rscale + M;                            // 32 KiB

  prepA_kernel<<<2048 + 4096, 256, 0, stream>>>(x, rscale, rsinv, kern, Wq);
  prepB_kernel<<<512, 512, 0, stream>>>(x, rsinv, Xq);
  gemm_bin_kernel<<<dim3(N / BN, M / BM), 512, 0, stream>>>(Xq, Wq, rscale, bias, out);
}